// Round 1
// baseline (17593.707 us; speedup 1.0000x reference)
//
#include <hip/hip_runtime.h>
#include <hip/hip_bf16.h>

typedef __hip_bfloat16 bf16;
typedef __attribute__((ext_vector_type(8))) short bf8;
typedef __attribute__((ext_vector_type(4))) float f4;
#define MFMA(a, b, c) __builtin_amdgcn_mfma_f32_16x16x32_bf16(a, b, c, 0, 0, 0)

#define B_SZ 512
#define TT 76
#define NSTEP 64
#define MLPH 15000
#define MLPH_PAD 15040

// hbuf layout: [parity][layer][batch 512][k 256] bf16
#define HIDX(p, l, b, k) (((((p) * 8 + (l)) * 512 + (b)) << 8) + (k))

__device__ __forceinline__ bf8 ldb8(const bf16* p) { return *reinterpret_cast<const bf8*>(p); }
__device__ __forceinline__ float sigf(float x) { return 1.f / (1.f + __expf(-x)); }
__device__ __forceinline__ float tanh_(float x) { float e = __expf(2.f * x); return 1.f - 2.f / (e + 1.f); }

// ---------------- barrier among 32 blocks of a group ----------------
__device__ __forceinline__ void group_barrier(unsigned* bar, unsigned& gen) {
    __syncthreads();                       // all block threads' stores issued (vmcnt drained)
    if (threadIdx.x == 0) {
        __threadfence();                   // flush this XCD's L2 (release, agent scope)
        unsigned arrived = __hip_atomic_fetch_add(&bar[0], 1u, __ATOMIC_ACQ_REL, __HIP_MEMORY_SCOPE_AGENT);
        if (arrived == 31u) {
            __hip_atomic_store(&bar[0], 0u, __ATOMIC_RELAXED, __HIP_MEMORY_SCOPE_AGENT);
            __hip_atomic_fetch_add(&bar[1], 1u, __ATOMIC_RELEASE, __HIP_MEMORY_SCOPE_AGENT);
        } else {
            while (__hip_atomic_load(&bar[1], __ATOMIC_ACQUIRE, __HIP_MEMORY_SCOPE_AGENT) <= gen) {
                __builtin_amdgcn_s_sleep(2);
            }
        }
        __threadfence();                   // acquire: invalidate stale L1/L2
    }
    __syncthreads();
    gen++;
}

// ---------------- small prep kernels ----------------
__global__ void k_zero_bar(unsigned* bars) {
    if (threadIdx.x < 256) bars[threadIdx.x] = 0u;
}

// Pack LSTM weights: Wp[l][np 0..1023][k 0..511] bf16.
// np: chunk c=np>>5 (8 h-units), r=np&31: gate gt=r>>3, unit u=r&7 -> orig row gt*256 + c*8 + u.
// k: l==0: k<32 = Wih0 cols (pad 14->32), k in [32,288) = Whh0, else 0.
//    l>=1: k<256 = Wih, k in [256,512) = Whh.
__global__ void k_pack(const float* Wih0, const float* Whh0, const float* bih0, const float* bhh0,
                       const float* Wih, const float* Whh, const float* bih, const float* bhh,
                       bf16* Wp, float* biasp) {
    int row = blockIdx.x;                 // 0..8191
    int l = row >> 10, np = row & 1023;
    int c = np >> 5, r = np & 31, gt = r >> 3, u = r & 7;
    int orig = gt * 256 + c * 8 + u;
    int tid = threadIdx.x;                // 128 threads, 4 k each
    for (int kk = 0; kk < 4; ++kk) {
        int k = tid * 4 + kk;
        float v;
        if (l == 0) {
            if (k < 32)       v = (k < 14) ? Wih0[orig * 14 + k] : 0.f;
            else if (k < 288) v = Whh0[orig * 256 + (k - 32)];
            else              v = 0.f;
        } else {
            if (k < 256) v = Wih[((l - 1) * 1024 + orig) * 256 + k];
            else         v = Whh[((l - 1) * 1024 + orig) * 256 + (k - 256)];
        }
        Wp[(size_t)row * 512 + k] = __float2bfloat16(v);
    }
    if (tid == 0) {
        biasp[row] = (l == 0) ? (bih0[orig] + bhh0[orig])
                              : (bih[(l - 1) * 1024 + orig] + bhh[(l - 1) * 1024 + orig]);
    }
}

__global__ void k_pack_fc(const float* Wfc, bf16* WfcP) {
    // WfcP [16][256], rows 9..15 zero
    for (int i = threadIdx.x; i < 16 * 256; i += 256) {
        int n = i >> 8, k = i & 255;
        float v = (n < 9) ? Wfc[n * 256 + k] : 0.f;
        WfcP[i] = __float2bfloat16(v);
    }
}

__global__ void k_build_enc(const float* states, const float* acts, bf16* enc) {
    int idx = blockIdx.x * 256 + threadIdx.x;
    if (idx >= B_SZ * 160) return;
    int b = idx / 160, k = idx - b * 160;
    float v = 0.f;
    if (k < 130) {
        int t = k / 13, d = k - t * 13;
        v = (d < 9) ? states[(b * TT + t) * 12 + 3 + d] : acts[(b * TT + t) * 4 + (d - 9)];
    }
    enc[idx] = __float2bfloat16(v);
}

// ---------------- GEMM1: mlp = relu(enc @ W1^T + b1) ----------------
// M=512 N=15040(pad) K=160(pad). grid: (blockIdx&7)=m-tile64, (>>3)=n-tile64 (235)
__launch_bounds__(256)
__global__ void k_gemm1(const bf16* enc, const float* W1, const float* b1, bf16* mlp) {
    __shared__ __align__(16) bf16 As[64 * 160];
    __shared__ __align__(16) bf16 Bs[64 * 32];
    int mt = blockIdx.x & 7, nt = blockIdx.x >> 3;
    int m0 = mt * 64, n0 = nt * 64;
    int tid = threadIdx.x, wv = tid >> 6, lane = tid & 63, col = lane & 15, quad = lane >> 4;

    for (int i = tid; i < 1280; i += 256) {  // 64*160/8
        int r = i / 20, cs = i - r * 20;
        *reinterpret_cast<uint4*>(&As[r * 160 + cs * 8]) =
            *reinterpret_cast<const uint4*>(&enc[(m0 + r) * 160 + cs * 8]);
    }

    f4 acc[4];
#pragma unroll
    for (int nti = 0; nti < 4; ++nti) {
        int ng = n0 + nti * 16 + col;
        float bv = (ng < MLPH) ? b1[ng] : 0.f;
        acc[nti] = (f4){bv, bv, bv, bv};
    }

    for (int ks = 0; ks < 5; ++ks) {
        {
            int n = tid >> 2, seg = tid & 3, ng = n0 + n;
#pragma unroll
            for (int j = 0; j < 8; ++j) {
                int k = ks * 32 + seg * 8 + j;
                float v = (ng < MLPH && k < 130) ? W1[ng * 130 + k] : 0.f;
                Bs[n * 32 + seg * 8 + j] = __float2bfloat16(v);
            }
        }
        __syncthreads();
        bf8 a = ldb8(&As[(wv * 16 + col) * 160 + ks * 32 + quad * 8]);
#pragma unroll
        for (int nti = 0; nti < 4; ++nti)
            acc[nti] = MFMA(a, ldb8(&Bs[(nti * 16 + col) * 32 + quad * 8]), acc[nti]);
        __syncthreads();
    }
#pragma unroll
    for (int nti = 0; nti < 4; ++nti) {
        int ng = n0 + nti * 16 + col;
#pragma unroll
        for (int r = 0; r < 4; ++r) {
            int row = m0 + wv * 16 + quad * 4 + r;
            mlp[(size_t)row * MLPH_PAD + ng] = __float2bfloat16(fmaxf(acc[nti][r], 0.f));
        }
    }
}

// ---------------- GEMM2: hc = mlp @ W2^T + b2 ----------------
// M=512 N=4096 K=15040. M-tile 128, N-tile 64. grid 256: (blockIdx&3)=mt, (>>2)=nt
__launch_bounds__(256)
__global__ void k_gemm2(const bf16* mlp, const float* W2, const float* b2, float* hc) {
    __shared__ __align__(16) bf16 As[128 * 32];
    __shared__ __align__(16) bf16 Bs[64 * 32];
    int mt = blockIdx.x & 3, nt = blockIdx.x >> 2;
    int m0 = mt * 128, n0 = nt * 64;
    int tid = threadIdx.x, wv = tid >> 6, lane = tid & 63, col = lane & 15, quad = lane >> 4;

    f4 acc[2][4];
#pragma unroll
    for (int i = 0; i < 2; ++i)
#pragma unroll
        for (int j = 0; j < 4; ++j) acc[i][j] = (f4){0.f, 0.f, 0.f, 0.f};

    for (int ks = 0; ks < 470; ++ks) {
        int k0 = ks * 32;
#pragma unroll
        for (int rep = 0; rep < 2; ++rep) {  // A: 128 rows x 32k
            int slot = tid + rep * 256;
            int r = slot >> 2, seg = slot & 3;
            *reinterpret_cast<uint4*>(&As[r * 32 + seg * 8]) =
                *reinterpret_cast<const uint4*>(&mlp[(size_t)(m0 + r) * MLPH_PAD + k0 + seg * 8]);
        }
#pragma unroll
        for (int rep = 0; rep < 2; ++rep) {  // B: 64 rows x 32k fp32 -> bf16
            int slot = tid + rep * 256;
            int n = slot >> 3, seg = slot & 7;
            int kb = k0 + seg * 4;
            const float* src = &W2[(size_t)(n0 + n) * MLPH + kb];
            float4 v;
            if (kb + 4 <= MLPH) v = *reinterpret_cast<const float4*>(src);
            else {
                v.x = (kb + 0 < MLPH) ? src[0] : 0.f;
                v.y = (kb + 1 < MLPH) ? src[1] : 0.f;
                v.z = (kb + 2 < MLPH) ? src[2] : 0.f;
                v.w = (kb + 3 < MLPH) ? src[3] : 0.f;
            }
            union { bf16 e[4]; uint2 u; } pk;
            pk.e[0] = __float2bfloat16(v.x); pk.e[1] = __float2bfloat16(v.y);
            pk.e[2] = __float2bfloat16(v.z); pk.e[3] = __float2bfloat16(v.w);
            *reinterpret_cast<uint2*>(&Bs[n * 32 + seg * 4]) = pk.u;
        }
        __syncthreads();
        bf8 a0 = ldb8(&As[(wv * 16 + col) * 32 + quad * 8]);
        bf8 a1 = ldb8(&As[((wv + 4) * 16 + col) * 32 + quad * 8]);
#pragma unroll
        for (int nti = 0; nti < 4; ++nti) {
            bf8 b = ldb8(&Bs[(nti * 16 + col) * 32 + quad * 8]);
            acc[0][nti] = MFMA(a0, b, acc[0][nti]);
            acc[1][nti] = MFMA(a1, b, acc[1][nti]);
        }
        __syncthreads();
    }
#pragma unroll
    for (int mi = 0; mi < 2; ++mi)
#pragma unroll
        for (int nti = 0; nti < 4; ++nti) {
            int ng = n0 + nti * 16 + col;
            float bv = b2[ng];
#pragma unroll
            for (int r = 0; r < 4; ++r) {
                int row = m0 + (wv + mi * 4) * 16 + quad * 4 + r;
                hc[(size_t)row * 4096 + ng] = acc[mi][nti][r] + bv;
            }
        }
}

// ---------------- LSTM rollout ----------------
// 256 blocks x 256 threads. group g = blockIdx&7 (batch slice 64), slice s = blockIdx>>3
// (32 packed gate-rows = 8 hidden units x 4 gates). 513 group barriers total.
__launch_bounds__(256)
__global__ void k_rollout(const float* states, const float* acts, const float* dts,
                          const float* bfc, const bf16* Wp, const float* biasp,
                          const bf16* WfcP, const float* hc,
                          bf16* hbuf, unsigned* bars, float* out) {
    const int g = blockIdx.x & 7, s = blockIdx.x >> 3;
    const int tid = threadIdx.x, wv = tid >> 6, lane = tid & 63, col = lane & 15, quad = lane >> 4;
    const int batch0 = g * 64, n0s = s * 32, j0 = s * 8;
    unsigned* bar = bars + g * 32;

    __shared__ float c_lds[8][64][8];
    __shared__ float pred_lds[64][12];
    __shared__ float gs[4][16][32];
    __shared__ __align__(16) bf16 x0_lds[64 * 32];

    unsigned my_gen = 0;

    // ---- init ----
    for (int i = tid; i < 576; i += 256) {
        int m = i / 9, o = i - m * 9;
        pred_lds[m][o] = states[((batch0 + m) * TT + 10) * 12 + 3 + o];
    }
    for (int i = tid; i < 4096; i += 256) {
        int l = i >> 9, r = i & 511, m = r >> 3, u = r & 7;
        c_lds[l][m][u] = hc[(size_t)(batch0 + m) * 4096 + l * 512 + 256 + j0 + u];
    }
    {
        int l = s & 7, q = s >> 3;
        for (int i = tid; i < 4096; i += 256) {
            int m = q * 16 + (i >> 8), k = i & 255;
            hbuf[HIDX(1, l, batch0 + m, k)] =
                __float2bfloat16(hc[(size_t)(batch0 + m) * 4096 + l * 512 + k]);
        }
    }
    group_barrier(bar, my_gen);

    for (int t = 0; t < NSTEP; ++t) {
        const int pw = t & 1, pr = pw ^ 1;
        // build x0 = [dt, pred(9), act(4), 0-pad] (bf16, K=32)
        if (tid < 64) {
            int m = tid, b = batch0 + m;
            bf16* row = &x0_lds[m * 32];
            row[0] = __float2bfloat16(dts[b * TT + 11 + t]);
#pragma unroll
            for (int o = 0; o < 9; ++o) row[1 + o] = __float2bfloat16(pred_lds[m][o]);
#pragma unroll
            for (int j = 0; j < 4; ++j) row[10 + j] = __float2bfloat16(acts[(b * TT + 10 + t) * 4 + j]);
#pragma unroll
            for (int k = 14; k < 32; ++k) row[k] = __float2bfloat16(0.f);
        }
        __syncthreads();

        for (int l = 0; l < 8; ++l) {
            float bv0 = biasp[l * 1024 + n0s + col];
            float bv1 = biasp[l * 1024 + n0s + 16 + col];
            f4 acc0 = (f4){bv0, bv0, bv0, bv0};
            f4 acc1 = (f4){bv1, bv1, bv1, bv1};
            const bf16* w0 = Wp + (size_t)(l * 1024 + n0s + col) * 512 + quad * 8;
            const bf16* w1 = w0 + 16 * 512;
            const int am = batch0 + wv * 16 + col;
            const bf16* hsrc = hbuf + HIDX(pr, l, am, quad * 8);
            if (l == 0) {
                bf8 a = ldb8(&x0_lds[(wv * 16 + col) * 32 + quad * 8]);
                acc0 = MFMA(a, ldb8(w0), acc0);
                acc1 = MFMA(a, ldb8(w1), acc1);
#pragma unroll
                for (int ks = 1; ks < 9; ++ks) {
                    a = ldb8(hsrc + (ks - 1) * 32);
                    acc0 = MFMA(a, ldb8(w0 + ks * 32), acc0);
                    acc1 = MFMA(a, ldb8(w1 + ks * 32), acc1);
                }
            } else {
                const bf16* xsrc = hbuf + HIDX(pw, l - 1, am, quad * 8);
#pragma unroll
                for (int ks = 0; ks < 8; ++ks) {
                    bf8 a = ldb8(xsrc + ks * 32);
                    acc0 = MFMA(a, ldb8(w0 + ks * 32), acc0);
                    acc1 = MFMA(a, ldb8(w1 + ks * 32), acc1);
                }
#pragma unroll
                for (int ks = 0; ks < 8; ++ks) {
                    bf8 a = ldb8(hsrc + ks * 32);
                    acc0 = MFMA(a, ldb8(w0 + 256 + ks * 32), acc0);
                    acc1 = MFMA(a, ldb8(w1 + 256 + ks * 32), acc1);
                }
            }
            // gates -> LDS (C layout: col=lane&15, row=quad*4+reg), then elementwise
#pragma unroll
            for (int r = 0; r < 4; ++r) {
                gs[wv][quad * 4 + r][col] = acc0[r];
                gs[wv][quad * 4 + r][col + 16] = acc1[r];
            }
#pragma unroll
            for (int pp = 0; pp < 2; ++pp) {
                int p = lane * 2 + pp;
                int mloc = p >> 3, u = p & 7;
                float iv = gs[wv][mloc][u], fv = gs[wv][mloc][8 + u];
                float gv = gs[wv][mloc][16 + u], ov = gs[wv][mloc][24 + u];
                int mg = wv * 16 + mloc;
                float cold = c_lds[l][mg][u];
                float cn = sigf(fv) * cold + sigf(iv) * tanh_(gv);
                float hn = sigf(ov) * tanh_(cn);
                c_lds[l][mg][u] = cn;
                hbuf[HIDX(pw, l, batch0 + mg, j0 + u)] = __float2bfloat16(hn);
            }
            group_barrier(bar, my_gen);
        }

        // fc: pred = h7 @ Wfc^T + bfc  (tiny MFMA, redundant per block)
        {
            float bv = (col < 9) ? bfc[col] : 0.f;
            f4 acc = (f4){bv, bv, bv, bv};
            const int am = batch0 + wv * 16 + col;
            const bf16* arow = hbuf + HIDX(pw, 7, am, quad * 8);
            const bf16* brow = WfcP + col * 256 + quad * 8;
#pragma unroll
            for (int ks = 0; ks < 8; ++ks)
                acc = MFMA(ldb8(arow + ks * 32), ldb8(brow + ks * 32), acc);
            if (col < 9) {
#pragma unroll
                for (int r = 0; r < 4; ++r) {
                    int mg = wv * 16 + quad * 4 + r;
                    pred_lds[mg][col] = acc[r];
                    if (s == 0) out[((size_t)(batch0 + mg) * NSTEP + t) * 9 + col] = acc[r];
                }
            }
            __syncthreads();
        }
    }
}

// ---------------- launch ----------------
extern "C" void kernel_launch(void* const* d_in, const int* in_sizes, int n_in,
                              void* d_out, int out_size, void* d_ws, size_t ws_size,
                              hipStream_t stream) {
    const float* states = (const float*)d_in[0];
    const float* acts   = (const float*)d_in[1];
    const float* dts    = (const float*)d_in[2];
    const float* W1     = (const float*)d_in[3];
    const float* b1     = (const float*)d_in[4];
    const float* W2     = (const float*)d_in[5];
    const float* b2     = (const float*)d_in[6];
    const float* Wih0   = (const float*)d_in[7];
    const float* Whh0   = (const float*)d_in[8];
    const float* bih0   = (const float*)d_in[9];
    const float* bhh0   = (const float*)d_in[10];
    const float* Wih    = (const float*)d_in[11];
    const float* Whh    = (const float*)d_in[12];
    const float* bih    = (const float*)d_in[13];
    const float* bhh    = (const float*)d_in[14];
    const float* Wfc    = (const float*)d_in[15];
    const float* bfc    = (const float*)d_in[16];
    float* out = (float*)d_out;

    char* w = (char*)d_ws;  // needs ~36.6 MB
    bf16*  Wp    = (bf16*)(w);                       // 8*1024*512*2   = 8,388,608
    float* biasp = (float*)(w + 8388608);            // 8*1024*4       = 32,768
    bf16*  WfcP  = (bf16*)(w + 8421376);             // 16*256*2       = 8,192
    bf16*  enc   = (bf16*)(w + 8429568);             // 512*160*2      = 163,840
    bf16*  mlp   = (bf16*)(w + 8593408);             // 512*15040*2    = 15,400,960
    float* hc    = (float*)(w + 23994368);           // 512*4096*4     = 8,388,608
    bf16*  hbuf  = (bf16*)(w + 32382976);            // 2*8*512*256*2  = 4,194,304
    unsigned* bars = (unsigned*)(w + 36577280);      // 1,024

    k_zero_bar<<<1, 256, 0, stream>>>(bars);
    k_pack<<<8192, 128, 0, stream>>>(Wih0, Whh0, bih0, bhh0, Wih, Whh, bih, bhh, Wp, biasp);
    k_pack_fc<<<1, 256, 0, stream>>>(Wfc, WfcP);
    k_build_enc<<<(B_SZ * 160 + 255) / 256, 256, 0, stream>>>(states, acts, enc);
    k_gemm1<<<8 * 235, 256, 0, stream>>>(enc, W1, b1, mlp);
    k_gemm2<<<256, 256, 0, stream>>>(mlp, W2, b2, hc);
    k_rollout<<<256, 256, 0, stream>>>(states, acts, dts, bfc, Wp, biasp, WfcP, hc, hbuf, bars, out);
}

// Round 2
// 5589.049 us; speedup vs baseline: 3.1479x; 3.1479x over previous
//
#include <hip/hip_runtime.h>
#include <hip/hip_bf16.h>

typedef __hip_bfloat16 bf16;
typedef __attribute__((ext_vector_type(8))) short bf8;
typedef __attribute__((ext_vector_type(4))) float f4;
#define MFMA(a, b, c) __builtin_amdgcn_mfma_f32_16x16x32_bf16(a, b, c, 0, 0, 0)

#define B_SZ 512
#define TT 76
#define NSTEP 64
#define MLPH 15000
#define MLPH_PAD 15040

// hbuf layout: [parity][layer][batch 512][k 256] bf16
#define HIDX(p, l, b, k) (((((p) * 8 + (l)) * 512 + (b)) << 8) + (k))

__device__ __forceinline__ bf8 ldb8(const bf16* p) { return *reinterpret_cast<const bf8*>(p); }
__device__ __forceinline__ float sigf(float x) { return 1.f / (1.f + __expf(-x)); }
__device__ __forceinline__ float tanh_(float x) { float e = __expf(2.f * x); return 1.f - 2.f / (e + 1.f); }

// Coherent (L1/L2-bypassing, sc0 sc1) accesses for cross-XCD h exchange.
// No cache-wide fences anywhere: weights stay L1/L2-hot.
__device__ __forceinline__ bf8 ld_coh8(const bf16* p) {
    union { unsigned long long q[2]; bf8 v; } u;
    const unsigned long long* qp = reinterpret_cast<const unsigned long long*>(p);
    u.q[0] = __hip_atomic_load(qp, __ATOMIC_RELAXED, __HIP_MEMORY_SCOPE_AGENT);
    u.q[1] = __hip_atomic_load(qp + 1, __ATOMIC_RELAXED, __HIP_MEMORY_SCOPE_AGENT);
    return u.v;
}
__device__ __forceinline__ void st_coh_u32(bf16* p, unsigned v) {
    __hip_atomic_store(reinterpret_cast<unsigned*>(p), v, __ATOMIC_RELAXED, __HIP_MEMORY_SCOPE_AGENT);
}

// Flag barrier among the 32 blocks of a group. gflags: [32 blocks][32 uints]
// (128 B spacing). Monotone generations; no resets, no fetch-add serialization,
// no threadfence. __syncthreads() drains vmcnt(0) per wave (compiler-emitted
// before s_barrier), so all coherent h-stores are LLC-visible before the flag.
__device__ __forceinline__ void group_barrier(unsigned* gflags, int myblk, unsigned& gen) {
    gen++;
    __syncthreads();
    if (threadIdx.x == 0)
        __hip_atomic_store(&gflags[myblk * 32], gen, __ATOMIC_RELAXED, __HIP_MEMORY_SCOPE_AGENT);
    if (threadIdx.x < 32) {
        while (__hip_atomic_load(&gflags[threadIdx.x * 32], __ATOMIC_RELAXED,
                                 __HIP_MEMORY_SCOPE_AGENT) < gen)
            __builtin_amdgcn_s_sleep(1);
    }
    __syncthreads();
}

// ---------------- small prep kernels ----------------
__global__ void k_zero_bar(unsigned* flags) {   // <<<32,256>>> zeroes 8192 uints
    flags[blockIdx.x * 256 + threadIdx.x] = 0u;
}

// Pack LSTM weights: Wp[l][np 0..1023][k 0..511] bf16.
// np: chunk c=np>>5 (8 h-units), r=np&31: gate gt=r>>3, unit u=r&7 -> orig row gt*256 + c*8 + u.
// k: l==0: k<32 = Wih0 cols (pad 14->32), k in [32,288) = Whh0, else 0.
//    l>=1: k<256 = Wih, k in [256,512) = Whh.
__global__ void k_pack(const float* Wih0, const float* Whh0, const float* bih0, const float* bhh0,
                       const float* Wih, const float* Whh, const float* bih, const float* bhh,
                       bf16* Wp, float* biasp) {
    int row = blockIdx.x;                 // 0..8191
    int l = row >> 10, np = row & 1023;
    int c = np >> 5, r = np & 31, gt = r >> 3, u = r & 7;
    int orig = gt * 256 + c * 8 + u;
    int tid = threadIdx.x;                // 128 threads, 4 k each
    for (int kk = 0; kk < 4; ++kk) {
        int k = tid * 4 + kk;
        float v;
        if (l == 0) {
            if (k < 32)       v = (k < 14) ? Wih0[orig * 14 + k] : 0.f;
            else if (k < 288) v = Whh0[orig * 256 + (k - 32)];
            else              v = 0.f;
        } else {
            if (k < 256) v = Wih[((l - 1) * 1024 + orig) * 256 + k];
            else         v = Whh[((l - 1) * 1024 + orig) * 256 + (k - 256)];
        }
        Wp[(size_t)row * 512 + k] = __float2bfloat16(v);
    }
    if (tid == 0) {
        biasp[row] = (l == 0) ? (bih0[orig] + bhh0[orig])
                              : (bih[(l - 1) * 1024 + orig] + bhh[(l - 1) * 1024 + orig]);
    }
}

__global__ void k_pack_fc(const float* Wfc, bf16* WfcP) {
    // WfcP [16][256], rows 9..15 zero
    for (int i = threadIdx.x; i < 16 * 256; i += 256) {
        int n = i >> 8, k = i & 255;
        float v = (n < 9) ? Wfc[n * 256 + k] : 0.f;
        WfcP[i] = __float2bfloat16(v);
    }
}

__global__ void k_build_enc(const float* states, const float* acts, bf16* enc) {
    int idx = blockIdx.x * 256 + threadIdx.x;
    if (idx >= B_SZ * 160) return;
    int b = idx / 160, k = idx - b * 160;
    float v = 0.f;
    if (k < 130) {
        int t = k / 13, d = k - t * 13;
        v = (d < 9) ? states[(b * TT + t) * 12 + 3 + d] : acts[(b * TT + t) * 4 + (d - 9)];
    }
    enc[idx] = __float2bfloat16(v);
}

// ---------------- GEMM1: mlp = relu(enc @ W1^T + b1) ----------------
__launch_bounds__(256)
__global__ void k_gemm1(const bf16* enc, const float* W1, const float* b1, bf16* mlp) {
    __shared__ __align__(16) bf16 As[64 * 160];
    __shared__ __align__(16) bf16 Bs[64 * 32];
    int mt = blockIdx.x & 7, nt = blockIdx.x >> 3;
    int m0 = mt * 64, n0 = nt * 64;
    int tid = threadIdx.x, wv = tid >> 6, lane = tid & 63, col = lane & 15, quad = lane >> 4;

    for (int i = tid; i < 1280; i += 256) {
        int r = i / 20, cs = i - r * 20;
        *reinterpret_cast<uint4*>(&As[r * 160 + cs * 8]) =
            *reinterpret_cast<const uint4*>(&enc[(m0 + r) * 160 + cs * 8]);
    }

    f4 acc[4];
#pragma unroll
    for (int nti = 0; nti < 4; ++nti) {
        int ng = n0 + nti * 16 + col;
        float bv = (ng < MLPH) ? b1[ng] : 0.f;
        acc[nti] = (f4){bv, bv, bv, bv};
    }

    for (int ks = 0; ks < 5; ++ks) {
        {
            int n = tid >> 2, seg = tid & 3, ng = n0 + n;
#pragma unroll
            for (int j = 0; j < 8; ++j) {
                int k = ks * 32 + seg * 8 + j;
                float v = (ng < MLPH && k < 130) ? W1[ng * 130 + k] : 0.f;
                Bs[n * 32 + seg * 8 + j] = __float2bfloat16(v);
            }
        }
        __syncthreads();
        bf8 a = ldb8(&As[(wv * 16 + col) * 160 + ks * 32 + quad * 8]);
#pragma unroll
        for (int nti = 0; nti < 4; ++nti)
            acc[nti] = MFMA(a, ldb8(&Bs[(nti * 16 + col) * 32 + quad * 8]), acc[nti]);
        __syncthreads();
    }
#pragma unroll
    for (int nti = 0; nti < 4; ++nti) {
        int ng = n0 + nti * 16 + col;
#pragma unroll
        for (int r = 0; r < 4; ++r) {
            int row = m0 + wv * 16 + quad * 4 + r;
            mlp[(size_t)row * MLPH_PAD + ng] = __float2bfloat16(fmaxf(acc[nti][r], 0.f));
        }
    }
}

// ---------------- GEMM2: hc = mlp @ W2^T + b2 ----------------
__launch_bounds__(256)
__global__ void k_gemm2(const bf16* mlp, const float* W2, const float* b2, float* hc) {
    __shared__ __align__(16) bf16 As[128 * 32];
    __shared__ __align__(16) bf16 Bs[64 * 32];
    int mt = blockIdx.x & 3, nt = blockIdx.x >> 2;
    int m0 = mt * 128, n0 = nt * 64;
    int tid = threadIdx.x, wv = tid >> 6, lane = tid & 63, col = lane & 15, quad = lane >> 4;

    f4 acc[2][4];
#pragma unroll
    for (int i = 0; i < 2; ++i)
#pragma unroll
        for (int j = 0; j < 4; ++j) acc[i][j] = (f4){0.f, 0.f, 0.f, 0.f};

    for (int ks = 0; ks < 470; ++ks) {
        int k0 = ks * 32;
#pragma unroll
        for (int rep = 0; rep < 2; ++rep) {
            int slot = tid + rep * 256;
            int r = slot >> 2, seg = slot & 3;
            *reinterpret_cast<uint4*>(&As[r * 32 + seg * 8]) =
                *reinterpret_cast<const uint4*>(&mlp[(size_t)(m0 + r) * MLPH_PAD + k0 + seg * 8]);
        }
#pragma unroll
        for (int rep = 0; rep < 2; ++rep) {
            int slot = tid + rep * 256;
            int n = slot >> 3, seg = slot & 7;
            int kb = k0 + seg * 4;
            const float* src = &W2[(size_t)(n0 + n) * MLPH + kb];
            float4 v;
            if (kb + 4 <= MLPH) v = *reinterpret_cast<const float4*>(src);
            else {
                v.x = (kb + 0 < MLPH) ? src[0] : 0.f;
                v.y = (kb + 1 < MLPH) ? src[1] : 0.f;
                v.z = (kb + 2 < MLPH) ? src[2] : 0.f;
                v.w = (kb + 3 < MLPH) ? src[3] : 0.f;
            }
            union { bf16 e[4]; uint2 u; } pk;
            pk.e[0] = __float2bfloat16(v.x); pk.e[1] = __float2bfloat16(v.y);
            pk.e[2] = __float2bfloat16(v.z); pk.e[3] = __float2bfloat16(v.w);
            *reinterpret_cast<uint2*>(&Bs[n * 32 + seg * 4]) = pk.u;
        }
        __syncthreads();
        bf8 a0 = ldb8(&As[(wv * 16 + col) * 32 + quad * 8]);
        bf8 a1 = ldb8(&As[((wv + 4) * 16 + col) * 32 + quad * 8]);
#pragma unroll
        for (int nti = 0; nti < 4; ++nti) {
            bf8 b = ldb8(&Bs[(nti * 16 + col) * 32 + quad * 8]);
            acc[0][nti] = MFMA(a0, b, acc[0][nti]);
            acc[1][nti] = MFMA(a1, b, acc[1][nti]);
        }
        __syncthreads();
    }
#pragma unroll
    for (int mi = 0; mi < 2; ++mi)
#pragma unroll
        for (int nti = 0; nti < 4; ++nti) {
            int ng = n0 + nti * 16 + col;
            float bv = b2[ng];
#pragma unroll
            for (int r = 0; r < 4; ++r) {
                int row = m0 + (wv + mi * 4) * 16 + quad * 4 + r;
                hc[(size_t)row * 4096 + ng] = acc[mi][nti][r] + bv;
            }
        }
}

// ---------------- LSTM rollout ----------------
// 256 blocks x 256 threads. group g = blockIdx&7 (batch slice 64), slice s = blockIdx>>3
// (32 packed gate-rows = 8 hidden units x 4 gates). 513 flag barriers total.
__launch_bounds__(256)
__global__ void k_rollout(const float* states, const float* acts, const float* dts,
                          const float* bfc, const bf16* Wp, const float* biasp,
                          const bf16* WfcP, const float* hc,
                          bf16* hbuf, unsigned* flags, float* out) {
    const int g = blockIdx.x & 7, s = blockIdx.x >> 3;
    const int tid = threadIdx.x, wv = tid >> 6, lane = tid & 63, col = lane & 15, quad = lane >> 4;
    const int batch0 = g * 64, n0s = s * 32, j0 = s * 8;
    const int am = batch0 + wv * 16 + col;           // A-fragment row (batch)
    unsigned* gflags = flags + g * 32 * 32;

    __shared__ float c_lds[8][64][8];
    __shared__ float pred_lds[64][12];
    __shared__ float gs[4][16][32];
    __shared__ __align__(16) bf16 x0_lds[64 * 32];

    unsigned gen = 0;

    // ---- init ----
    for (int i = tid; i < 576; i += 256) {
        int m = i / 9, o = i - m * 9;
        pred_lds[m][o] = states[((batch0 + m) * TT + 10) * 12 + 3 + o];
    }
    for (int i = tid; i < 4096; i += 256) {
        int l = i >> 9, r = i & 511, m = r >> 3, u = r & 7;
        c_lds[l][m][u] = hc[(size_t)(batch0 + m) * 4096 + l * 512 + 256 + j0 + u];
    }
    {
        int l = s & 7, q = s >> 3;
        for (int i = tid; i < 2048; i += 256) {
            int m = q * 16 + (i >> 7), kk = (i & 127) * 2;
            union { bf16 e[2]; unsigned u; } pk;
            pk.e[0] = __float2bfloat16(hc[(size_t)(batch0 + m) * 4096 + l * 512 + kk]);
            pk.e[1] = __float2bfloat16(hc[(size_t)(batch0 + m) * 4096 + l * 512 + kk + 1]);
            st_coh_u32(&hbuf[HIDX(1, l, batch0 + m, kk)], pk.u);
        }
    }
    group_barrier(gflags, s, gen);

    // preload recurrent h for (t=0, l=0): parity 1, layer 0
    bf8 hrec[8];
    {
        const bf16* hn = hbuf + HIDX(1, 0, am, quad * 8);
#pragma unroll
        for (int ks = 0; ks < 8; ++ks) hrec[ks] = ld_coh8(hn + ks * 32);
    }

    for (int t = 0; t < NSTEP; ++t) {
        const int pw = t & 1, pr = pw ^ 1;
        // build x0 = [dt, pred(9), act(4), 0-pad] (bf16, K=32)
        if (tid < 64) {
            int m = tid, b = batch0 + m;
            bf16* row = &x0_lds[m * 32];
            row[0] = __float2bfloat16(dts[b * TT + 11 + t]);
#pragma unroll
            for (int o = 0; o < 9; ++o) row[1 + o] = __float2bfloat16(pred_lds[m][o]);
#pragma unroll
            for (int j = 0; j < 4; ++j) row[10 + j] = __float2bfloat16(acts[(b * TT + 10 + t) * 4 + j]);
#pragma unroll
            for (int k = 14; k < 32; ++k) row[k] = __float2bfloat16(0.f);
        }
        __syncthreads();

        for (int l = 0; l < 8; ++l) {
            float bv0 = biasp[l * 1024 + n0s + col];
            float bv1 = biasp[l * 1024 + n0s + 16 + col];
            f4 acc0 = (f4){bv0, bv0, bv0, bv0};
            f4 acc1 = (f4){bv1, bv1, bv1, bv1};
            const bf16* w0 = Wp + (size_t)(l * 1024 + n0s + col) * 512 + quad * 8;
            const bf16* w1 = w0 + 16 * 512;
            if (l == 0) {
                bf8 a = ldb8(&x0_lds[(wv * 16 + col) * 32 + quad * 8]);
                acc0 = MFMA(a, ldb8(w0), acc0);
                acc1 = MFMA(a, ldb8(w1), acc1);
#pragma unroll
                for (int ks = 0; ks < 8; ++ks) {
                    acc0 = MFMA(hrec[ks], ldb8(w0 + (ks + 1) * 32), acc0);
                    acc1 = MFMA(hrec[ks], ldb8(w1 + (ks + 1) * 32), acc1);
                }
            } else {
                bf8 xfr[8];
                const bf16* xsrc = hbuf + HIDX(pw, l - 1, am, quad * 8);
#pragma unroll
                for (int ks = 0; ks < 8; ++ks) xfr[ks] = ld_coh8(xsrc + ks * 32);
#pragma unroll
                for (int ks = 0; ks < 8; ++ks) {
                    acc0 = MFMA(xfr[ks], ldb8(w0 + ks * 32), acc0);
                    acc1 = MFMA(xfr[ks], ldb8(w1 + ks * 32), acc1);
                }
#pragma unroll
                for (int ks = 0; ks < 8; ++ks) {
                    acc0 = MFMA(hrec[ks], ldb8(w0 + 256 + ks * 32), acc0);
                    acc1 = MFMA(hrec[ks], ldb8(w1 + 256 + ks * 32), acc1);
                }
            }
            // prefetch next layer's recurrent h (written last step; in flight across barrier)
            if (l < 7) {
                const bf16* hn = hbuf + HIDX(pr, l + 1, am, quad * 8);
#pragma unroll
                for (int ks = 0; ks < 8; ++ks) hrec[ks] = ld_coh8(hn + ks * 32);
            }
            // gates -> LDS (C layout: col=lane&15, row=quad*4+reg), then elementwise
#pragma unroll
            for (int r = 0; r < 4; ++r) {
                gs[wv][quad * 4 + r][col] = acc0[r];
                gs[wv][quad * 4 + r][col + 16] = acc1[r];
            }
            {
                int p = lane * 2;
                int mloc = p >> 3, u = p & 7;          // u even; handle u and u+1
                int mg = wv * 16 + mloc;
                float iv0 = gs[wv][mloc][u],      fv0 = gs[wv][mloc][8 + u];
                float gv0 = gs[wv][mloc][16 + u], ov0 = gs[wv][mloc][24 + u];
                float iv1 = gs[wv][mloc][u + 1],      fv1 = gs[wv][mloc][9 + u];
                float gv1 = gs[wv][mloc][17 + u], ov1 = gs[wv][mloc][25 + u];
                float c0 = c_lds[l][mg][u], c1 = c_lds[l][mg][u + 1];
                float cn0 = sigf(fv0) * c0 + sigf(iv0) * tanh_(gv0);
                float cn1 = sigf(fv1) * c1 + sigf(iv1) * tanh_(gv1);
                float hn0 = sigf(ov0) * tanh_(cn0);
                float hn1 = sigf(ov1) * tanh_(cn1);
                c_lds[l][mg][u] = cn0; c_lds[l][mg][u + 1] = cn1;
                union { bf16 e[2]; unsigned uu; } pk;
                pk.e[0] = __float2bfloat16(hn0); pk.e[1] = __float2bfloat16(hn1);
                st_coh_u32(&hbuf[HIDX(pw, l, batch0 + mg, j0 + u)], pk.uu);
            }
            group_barrier(gflags, s, gen);
        }

        // fc: pred = h7 @ Wfc^T + bfc  (tiny MFMA, redundant per block)
        {
            float bv = (col < 9) ? bfc[col] : 0.f;
            f4 acc = (f4){bv, bv, bv, bv};
            const bf16* arow = hbuf + HIDX(pw, 7, am, quad * 8);
            bf8 hf[8];
#pragma unroll
            for (int ks = 0; ks < 8; ++ks) hf[ks] = ld_coh8(arow + ks * 32);
            const bf16* brow = WfcP + col * 256 + quad * 8;
#pragma unroll
            for (int ks = 0; ks < 8; ++ks) acc = MFMA(hf[ks], ldb8(brow + ks * 32), acc);
            if (col < 9) {
#pragma unroll
                for (int r = 0; r < 4; ++r) {
                    int mg = wv * 16 + quad * 4 + r;
                    pred_lds[mg][col] = acc[r];
                    if (s == 0) out[((size_t)(batch0 + mg) * NSTEP + t) * 9 + col] = acc[r];
                }
            }
            // prefetch next step's l=0 recurrent h: parity pw, layer 0 (already final)
            const bf16* hn = hbuf + HIDX(pw, 0, am, quad * 8);
#pragma unroll
            for (int ks = 0; ks < 8; ++ks) hrec[ks] = ld_coh8(hn + ks * 32);
            __syncthreads();
        }
    }
}

// ---------------- launch ----------------
extern "C" void kernel_launch(void* const* d_in, const int* in_sizes, int n_in,
                              void* d_out, int out_size, void* d_ws, size_t ws_size,
                              hipStream_t stream) {
    const float* states = (const float*)d_in[0];
    const float* acts   = (const float*)d_in[1];
    const float* dts    = (const float*)d_in[2];
    const float* W1     = (const float*)d_in[3];
    const float* b1     = (const float*)d_in[4];
    const float* W2     = (const float*)d_in[5];
    const float* b2     = (const float*)d_in[6];
    const float* Wih0   = (const float*)d_in[7];
    const float* Whh0   = (const float*)d_in[8];
    const float* bih0   = (const float*)d_in[9];
    const float* bhh0   = (const float*)d_in[10];
    const float* Wih    = (const float*)d_in[11];
    const float* Whh    = (const float*)d_in[12];
    const float* bih    = (const float*)d_in[13];
    const float* bhh    = (const float*)d_in[14];
    const float* Wfc    = (const float*)d_in[15];
    const float* bfc    = (const float*)d_in[16];
    float* out = (float*)d_out;

    char* w = (char*)d_ws;  // needs ~36.7 MB
    bf16*  Wp    = (bf16*)(w);                       // 8*1024*512*2   = 8,388,608
    float* biasp = (float*)(w + 8388608);            // 8*1024*4       = 32,768
    bf16*  WfcP  = (bf16*)(w + 8421376);             // 16*256*2       = 8,192
    bf16*  enc   = (bf16*)(w + 8429568);             // 512*160*2      = 163,840
    bf16*  mlp   = (bf16*)(w + 8593408);             // 512*15040*2    = 15,400,960
    float* hc    = (float*)(w + 23994368);           // 512*4096*4     = 8,388,608
    bf16*  hbuf  = (bf16*)(w + 32382976);            // 2*8*512*256*2  = 4,194,304
    unsigned* flags = (unsigned*)(w + 36577280);     // 8*32*32*4      = 32,768

    k_zero_bar<<<32, 256, 0, stream>>>(flags);
    k_pack<<<8192, 128, 0, stream>>>(Wih0, Whh0, bih0, bhh0, Wih, Whh, bih, bhh, Wp, biasp);
    k_pack_fc<<<1, 256, 0, stream>>>(Wfc, WfcP);
    k_build_enc<<<(B_SZ * 160 + 255) / 256, 256, 0, stream>>>(states, acts, enc);
    k_gemm1<<<8 * 235, 256, 0, stream>>>(enc, W1, b1, mlp);
    k_gemm2<<<256, 256, 0, stream>>>(mlp, W2, b2, hc);
    k_rollout<<<256, 256, 0, stream>>>(states, acts, dts, bfc, Wp, biasp, WfcP, hc, hbuf, flags, out);
}

// Round 3
// 5142.801 us; speedup vs baseline: 3.4210x; 1.0868x over previous
//
#include <hip/hip_runtime.h>
#include <hip/hip_bf16.h>

typedef __hip_bfloat16 bf16;
typedef __attribute__((ext_vector_type(8))) short bf8;
typedef __attribute__((ext_vector_type(4))) float f4;
#define MFMA(a, b, c) __builtin_amdgcn_mfma_f32_16x16x32_bf16(a, b, c, 0, 0, 0)

#define B_SZ 512
#define TT 76
#define NSTEP 64
#define MLPH 15000
#define MLPH_PAD 15040
#define XSP 264   // xs row stride (bf16): 256 + 8 pad (keeps 16B align, kills bank conflicts)

// hbuf layout: [parity][layer][batch 512][unit 256] bf16
#define HIDX(p, l, b, k) (((((p) * 8 + (l)) * 512 + (b)) << 8) + (k))
// flag index: [l][g][s][w], 64B spacing
#define FLG(l, g, s, w) (((((l) * 8 + (g)) * 4 + (s)) * 4 + (w)) * 16)

__device__ __forceinline__ bf8 ldb8(const bf16* p) { return *reinterpret_cast<const bf8*>(p); }
__device__ __forceinline__ float sigf(float x) { return 1.f / (1.f + __expf(-x)); }
__device__ __forceinline__ float tanh_(float x) { float e = __expf(2.f * x); return 1.f - 2.f / (e + 1.f); }

// Coherent (L1/L2-bypassing) ops for cross-XCD exchange. No cache-wide fences.
__device__ __forceinline__ bf8 ld_coh8(const bf16* p) {
    union { unsigned long long q[2]; bf8 v; } u;
    const unsigned long long* qp = reinterpret_cast<const unsigned long long*>(p);
    u.q[0] = __hip_atomic_load(qp, __ATOMIC_RELAXED, __HIP_MEMORY_SCOPE_AGENT);
    u.q[1] = __hip_atomic_load(qp + 1, __ATOMIC_RELAXED, __HIP_MEMORY_SCOPE_AGENT);
    return u.v;
}
__device__ __forceinline__ void st_coh_u32(bf16* p, unsigned v) {
    __hip_atomic_store(reinterpret_cast<unsigned*>(p), v, __ATOMIC_RELAXED, __HIP_MEMORY_SCOPE_AGENT);
}
__device__ __forceinline__ void st_flag(unsigned* p, unsigned v) {
    __hip_atomic_store(p, v, __ATOMIC_RELAXED, __HIP_MEMORY_SCOPE_AGENT);
}
// lanes 0..15 of each wave poll the 16 flags of (fl, fg); wave reconverges when all >= target
__device__ __forceinline__ void wait16(const unsigned* flags, int fl, int fg, unsigned target, int lane) {
    if (lane < 16) {
        const unsigned* fp = &flags[FLG(fl, fg, lane >> 2, lane & 3)];
        while (__hip_atomic_load(fp, __ATOMIC_RELAXED, __HIP_MEMORY_SCOPE_AGENT) < target)
            __builtin_amdgcn_s_sleep(1);
    }
}

// ---------------- small prep kernels ----------------
__global__ void k_zero_bar(unsigned* flags) {   // <<<64,256>>> zeroes 16384 uints
    flags[blockIdx.x * 256 + threadIdx.x] = 0u;
}

// Pack LSTM weights: Wp[l][np 0..1023][k 0..511] bf16.
// np: chunk c=np>>5 (8 h-units), r=np&31: gate gt=r>>3, unit u=r&7 -> orig row gt*256 + c*8 + u.
// k: l==0: k<32 = Wih0 cols (pad 14->32), k in [32,288) = Whh0, else 0.
//    l>=1: k<256 = Wih, k in [256,512) = Whh.
__global__ void k_pack(const float* Wih0, const float* Whh0, const float* bih0, const float* bhh0,
                       const float* Wih, const float* Whh, const float* bih, const float* bhh,
                       bf16* Wp, float* biasp) {
    int row = blockIdx.x;                 // 0..8191
    int l = row >> 10, np = row & 1023;
    int c = np >> 5, r = np & 31, gt = r >> 3, u = r & 7;
    int orig = gt * 256 + c * 8 + u;
    int tid = threadIdx.x;                // 128 threads, 4 k each
    for (int kk = 0; kk < 4; ++kk) {
        int k = tid * 4 + kk;
        float v;
        if (l == 0) {
            if (k < 32)       v = (k < 14) ? Wih0[orig * 14 + k] : 0.f;
            else if (k < 288) v = Whh0[orig * 256 + (k - 32)];
            else              v = 0.f;
        } else {
            if (k < 256) v = Wih[((l - 1) * 1024 + orig) * 256 + k];
            else         v = Whh[((l - 1) * 1024 + orig) * 256 + (k - 256)];
        }
        Wp[(size_t)row * 512 + k] = __float2bfloat16(v);
    }
    if (tid == 0) {
        biasp[row] = (l == 0) ? (bih0[orig] + bhh0[orig])
                              : (bih[(l - 1) * 1024 + orig] + bhh[(l - 1) * 1024 + orig]);
    }
}

__global__ void k_pack_fc(const float* Wfc, bf16* WfcP) {
    // WfcP [16][256], rows 9..15 zero
    for (int i = threadIdx.x; i < 16 * 256; i += 256) {
        int n = i >> 8, k = i & 255;
        float v = (n < 9) ? Wfc[n * 256 + k] : 0.f;
        WfcP[i] = __float2bfloat16(v);
    }
}

__global__ void k_build_enc(const float* states, const float* acts, bf16* enc) {
    int idx = blockIdx.x * 256 + threadIdx.x;
    if (idx >= B_SZ * 160) return;
    int b = idx / 160, k = idx - b * 160;
    float v = 0.f;
    if (k < 130) {
        int t = k / 13, d = k - t * 13;
        v = (d < 9) ? states[(b * TT + t) * 12 + 3 + d] : acts[(b * TT + t) * 4 + (d - 9)];
    }
    enc[idx] = __float2bfloat16(v);
}

// ---------------- GEMM1: mlp = relu(enc @ W1^T + b1) ----------------
__launch_bounds__(256)
__global__ void k_gemm1(const bf16* enc, const float* W1, const float* b1, bf16* mlp) {
    __shared__ __align__(16) bf16 As[64 * 160];
    __shared__ __align__(16) bf16 Bs[64 * 32];
    int mt = blockIdx.x & 7, nt = blockIdx.x >> 3;
    int m0 = mt * 64, n0 = nt * 64;
    int tid = threadIdx.x, wv = tid >> 6, lane = tid & 63, col = lane & 15, quad = lane >> 4;

    for (int i = tid; i < 1280; i += 256) {
        int r = i / 20, cs = i - r * 20;
        *reinterpret_cast<uint4*>(&As[r * 160 + cs * 8]) =
            *reinterpret_cast<const uint4*>(&enc[(m0 + r) * 160 + cs * 8]);
    }

    f4 acc[4];
#pragma unroll
    for (int nti = 0; nti < 4; ++nti) {
        int ng = n0 + nti * 16 + col;
        float bv = (ng < MLPH) ? b1[ng] : 0.f;
        acc[nti] = (f4){bv, bv, bv, bv};
    }

    for (int ks = 0; ks < 5; ++ks) {
        {
            int n = tid >> 2, seg = tid & 3, ng = n0 + n;
#pragma unroll
            for (int j = 0; j < 8; ++j) {
                int k = ks * 32 + seg * 8 + j;
                float v = (ng < MLPH && k < 130) ? W1[ng * 130 + k] : 0.f;
                Bs[n * 32 + seg * 8 + j] = __float2bfloat16(v);
            }
        }
        __syncthreads();
        bf8 a = ldb8(&As[(wv * 16 + col) * 160 + ks * 32 + quad * 8]);
#pragma unroll
        for (int nti = 0; nti < 4; ++nti)
            acc[nti] = MFMA(a, ldb8(&Bs[(nti * 16 + col) * 32 + quad * 8]), acc[nti]);
        __syncthreads();
    }
#pragma unroll
    for (int nti = 0; nti < 4; ++nti) {
        int ng = n0 + nti * 16 + col;
#pragma unroll
        for (int r = 0; r < 4; ++r) {
            int row = m0 + wv * 16 + quad * 4 + r;
            mlp[(size_t)row * MLPH_PAD + ng] = __float2bfloat16(fmaxf(acc[nti][r], 0.f));
        }
    }
}

// ---------------- GEMM2: hc = mlp @ W2^T + b2 ----------------
__launch_bounds__(256)
__global__ void k_gemm2(const bf16* mlp, const float* W2, const float* b2, float* hc) {
    __shared__ __align__(16) bf16 As[128 * 32];
    __shared__ __align__(16) bf16 Bs[64 * 32];
    int mt = blockIdx.x & 3, nt = blockIdx.x >> 2;
    int m0 = mt * 128, n0 = nt * 64;
    int tid = threadIdx.x, wv = tid >> 6, lane = tid & 63, col = lane & 15, quad = lane >> 4;

    f4 acc[2][4];
#pragma unroll
    for (int i = 0; i < 2; ++i)
#pragma unroll
        for (int j = 0; j < 4; ++j) acc[i][j] = (f4){0.f, 0.f, 0.f, 0.f};

    for (int ks = 0; ks < 470; ++ks) {
        int k0 = ks * 32;
#pragma unroll
        for (int rep = 0; rep < 2; ++rep) {
            int slot = tid + rep * 256;
            int r = slot >> 2, seg = slot & 3;
            *reinterpret_cast<uint4*>(&As[r * 32 + seg * 8]) =
                *reinterpret_cast<const uint4*>(&mlp[(size_t)(m0 + r) * MLPH_PAD + k0 + seg * 8]);
        }
#pragma unroll
        for (int rep = 0; rep < 2; ++rep) {
            int slot = tid + rep * 256;
            int n = slot >> 3, seg = slot & 7;
            int kb = k0 + seg * 4;
            const float* src = &W2[(size_t)(n0 + n) * MLPH + kb];
            float4 v;
            if (kb + 4 <= MLPH) v = *reinterpret_cast<const float4*>(src);
            else {
                v.x = (kb + 0 < MLPH) ? src[0] : 0.f;
                v.y = (kb + 1 < MLPH) ? src[1] : 0.f;
                v.z = (kb + 2 < MLPH) ? src[2] : 0.f;
                v.w = (kb + 3 < MLPH) ? src[3] : 0.f;
            }
            union { bf16 e[4]; uint2 u; } pk;
            pk.e[0] = __float2bfloat16(v.x); pk.e[1] = __float2bfloat16(v.y);
            pk.e[2] = __float2bfloat16(v.z); pk.e[3] = __float2bfloat16(v.w);
            *reinterpret_cast<uint2*>(&Bs[n * 32 + seg * 4]) = pk.u;
        }
        __syncthreads();
        bf8 a0 = ldb8(&As[(wv * 16 + col) * 32 + quad * 8]);
        bf8 a1 = ldb8(&As[((wv + 4) * 16 + col) * 32 + quad * 8]);
#pragma unroll
        for (int nti = 0; nti < 4; ++nti) {
            bf8 b = ldb8(&Bs[(nti * 16 + col) * 32 + quad * 8]);
            acc[0][nti] = MFMA(a0, b, acc[0][nti]);
            acc[1][nti] = MFMA(a1, b, acc[1][nti]);
        }
        __syncthreads();
    }
#pragma unroll
    for (int mi = 0; mi < 2; ++mi)
#pragma unroll
        for (int nti = 0; nti < 4; ++nti) {
            int ng = n0 + nti * 16 + col;
            float bv = b2[ng];
#pragma unroll
            for (int r = 0; r < 4; ++r) {
                int row = m0 + (wv + mi * 4) * 16 + quad * 4 + r;
                hc[(size_t)row * 4096 + ng] = acc[mi][nti][r] + bv;
            }
        }
}

// ---------------- LSTM rollout: per-layer pipeline ----------------
// 256 blocks x 256 threads. l = blockIdx&7 (one layer per XCD -> weights L2-resident),
// g = batch-group (64 rows), s = gate-slice (256 packed rows). Wave w owns packed rows
// [s*256+w*64, +64) = units [s*64+w*16, +16), all 64 batch rows.
// Critical path per hop: flag detect -> x stage to LDS -> 128 MFMAs (weights in VGPRs)
// -> elementwise -> h store + per-wave flag. Own-h half-GEMM runs in the 7-hop slack.
__launch_bounds__(256, 1)
__global__ void k_rollout(const float* states, const float* acts, const float* dts,
                          const float* bfc, const bf16* Wp, const float* biasp,
                          const bf16* WfcP, const float* hc,
                          bf16* hbuf, unsigned* flags, float* out) {
    const int l = blockIdx.x & 7, gsi = blockIdx.x >> 3, g = gsi >> 2, s = gsi & 3;
    const int tid = threadIdx.x, wv = tid >> 6, lane = tid & 63, col = lane & 15, quad = lane >> 4;
    const int batch0 = g * 64;
    const int nbase = l * 1024 + s * 256 + wv * 64;   // packed-row base for this wave

    __shared__ __align__(16) bf16 xs[64 * XSP];       // 33 KB staging (own-h, then x / h7)
    __shared__ float c_lds[4][16][65];                // per-wave c state
    __shared__ float gs_lds[4][16][33];               // per-wave gate exchange
    __shared__ float pred_lds[64][12];                // stage-0 only

    // ---- constants per block (hoisted out of t-loop) ----
    float bv[4];
    const bf16* wr[4];
#pragma unroll
    for (int nf = 0; nf < 4; ++nf) {
        bv[nf] = biasp[nbase + nf * 16 + col];
        wr[nf] = Wp + (size_t)(nbase + nf * 16 + col) * 512 + quad * 8;
    }
    // x-half weights resident in VGPRs (constant across all 64 steps)
    bf8 bx[4][8];   // l>=1: chunks 0..7. l==0: only bx[nf][0] (x0 chunk) used.
    if (l >= 1) {
#pragma unroll
        for (int nf = 0; nf < 4; ++nf)
#pragma unroll
            for (int kc = 0; kc < 8; ++kc) bx[nf][kc] = ldb8(wr[nf] + kc * 32);
    } else {
#pragma unroll
        for (int nf = 0; nf < 4; ++nf) bx[nf][0] = ldb8(wr[nf]);
    }
    bf8 bfcB[8];
    if (l == 0) {
#pragma unroll
        for (int kc = 0; kc < 8; ++kc) bfcB[kc] = ldb8(WfcP + col * 256 + kc * 32 + quad * 8);
    }

    // ---- init: h_l(-1) -> hbuf parity 1 (own units), c -> LDS, pred (stage 0) ----
    for (int i = tid; i < 2048; i += 256) {
        int m = i >> 5, du = i & 31;
        int u = s * 64 + du * 2;
        union { bf16 e[2]; unsigned uu; } pk;
        pk.e[0] = __float2bfloat16(hc[(size_t)(batch0 + m) * 4096 + l * 512 + u]);
        pk.e[1] = __float2bfloat16(hc[(size_t)(batch0 + m) * 4096 + l * 512 + u + 1]);
        st_coh_u32(&hbuf[HIDX(1, l, batch0 + m, u)], pk.uu);
    }
    for (int i = tid; i < 4096; i += 256) {
        int w = i >> 10, u = (i >> 6) & 15, m = i & 63;
        c_lds[w][u][m] = hc[(size_t)(batch0 + m) * 4096 + l * 512 + 256 + s * 64 + w * 16 + u];
    }
    if (l == 0) {
        for (int i = tid; i < 576; i += 256) {
            int m = i / 9, o = i - m * 9;
            pred_lds[m][o] = states[((batch0 + m) * TT + 10) * 12 + 3 + o];
        }
    }
    __syncthreads();                                   // drains vmcnt -> init stores visible
    if (tid < 4) st_flag(&flags[FLG(l, g, s, tid)], 1u);

    f4 acc[4][4];
    for (int t = 0; t <= NSTEP; ++t) {
        const int pw = t & 1, pr = pw ^ 1;

        // ---- [A] own-h staging + h-half GEMM (7 hops of slack; off critical path) ----
        if (t < NSTEP) {
            wait16(flags, l, g, (unsigned)(t + 1), lane);   // siblings' h_l(t-1) stored
            __syncthreads();                                // xs free from prior iter
            for (int i = tid; i < 2048; i += 256) {
                int row = i >> 5, seg = i & 31;
                bf8 v = ld_coh8(&hbuf[HIDX(pr, l, batch0 + row, seg * 8)]);
                *reinterpret_cast<bf8*>(&xs[row * XSP + seg * 8]) = v;
            }
            __syncthreads();
#pragma unroll
            for (int nf = 0; nf < 4; ++nf)
#pragma unroll
                for (int mi = 0; mi < 4; ++mi) acc[mi][nf] = (f4){bv[nf], bv[nf], bv[nf], bv[nf]};
            const int hk0 = (l == 0) ? 1 : 8;               // weight chunk base for h-half
#pragma unroll
            for (int kc = 0; kc < 8; ++kc) {
                bf8 af[4];
#pragma unroll
                for (int mi = 0; mi < 4; ++mi)
                    af[mi] = ldb8(&xs[(mi * 16 + col) * XSP + kc * 32 + quad * 8]);
#pragma unroll
                for (int nf = 0; nf < 4; ++nf) {
                    bf8 b = ldb8(wr[nf] + (hk0 + kc) * 32);
#pragma unroll
                    for (int mi = 0; mi < 4; ++mi) acc[mi][nf] = MFMA(af[mi], b, acc[mi][nf]);
                }
            }
            __syncthreads();                                // xs free for restage
        }

        // ---- [B] x acquisition + x-half GEMM (critical path) ----
        if (l == 0) {
            if (t >= 1) {
                wait16(flags, 7, g, (unsigned)(t + 1), lane);   // h7(t-1) stored
                for (int i = tid; i < 2048; i += 256) {
                    int row = i >> 5, seg = i & 31;
                    bf8 v = ld_coh8(&hbuf[HIDX(pr, 7, batch0 + row, seg * 8)]);
                    *reinterpret_cast<bf8*>(&xs[row * XSP + seg * 8]) = v;
                }
                __syncthreads();
                // fc: pred(t-1) = h7(t-1) @ Wfc^T + bfc ; wave w = m-frag w
                float bvfc = (col < 9) ? bfc[col] : 0.f;
                f4 fa = (f4){bvfc, bvfc, bvfc, bvfc};
#pragma unroll
                for (int kc = 0; kc < 8; ++kc)
                    fa = MFMA(ldb8(&xs[(wv * 16 + col) * XSP + kc * 32 + quad * 8]), bfcB[kc], fa);
                if (col < 9) {
#pragma unroll
                    for (int r = 0; r < 4; ++r) {
                        int m = wv * 16 + quad * 4 + r;
                        pred_lds[m][col] = fa[r];
                        if (s == 0) out[((size_t)(batch0 + m) * NSTEP + (t - 1)) * 9 + col] = fa[r];
                    }
                }
                __syncthreads();
            }
            if (t == NSTEP) break;
            // gather x0 A-frags: [dt, pred(9), act(4), 0-pad] K=32
#pragma unroll
            for (int mi = 0; mi < 4; ++mi) {
                int mrow = mi * 16 + col, b = batch0 + mrow;
                union { bf16 e[8]; bf8 v; } pk;
#pragma unroll
                for (int j = 0; j < 8; ++j) {
                    int k = quad * 8 + j;
                    float x;
                    if (k == 0)       x = dts[b * TT + 11 + t];
                    else if (k < 10)  x = pred_lds[mrow][k - 1];
                    else if (k < 14)  x = acts[(b * TT + 10 + t) * 4 + (k - 10)];
                    else              x = 0.f;
                    pk.e[j] = __float2bfloat16(x);
                }
#pragma unroll
                for (int nf = 0; nf < 4; ++nf) acc[mi][nf] = MFMA(pk.v, bx[nf][0], acc[mi][nf]);
            }
        } else {
            if (t == NSTEP) break;
            wait16(flags, l - 1, g, (unsigned)(t + 2), lane);   // h_{l-1}(t) stored
            for (int i = tid; i < 2048; i += 256) {
                int row = i >> 5, seg = i & 31;
                bf8 v = ld_coh8(&hbuf[HIDX(pw, l - 1, batch0 + row, seg * 8)]);
                *reinterpret_cast<bf8*>(&xs[row * XSP + seg * 8]) = v;
            }
            __syncthreads();
#pragma unroll
            for (int kc = 0; kc < 8; ++kc) {
                bf8 af[4];
#pragma unroll
                for (int mi = 0; mi < 4; ++mi)
                    af[mi] = ldb8(&xs[(mi * 16 + col) * XSP + kc * 32 + quad * 8]);
#pragma unroll
                for (int nf = 0; nf < 4; ++nf)
#pragma unroll
                    for (int mi = 0; mi < 4; ++mi)
                        acc[mi][nf] = MFMA(af[mi], bx[nf][kc], acc[mi][nf]);
            }
        }

        // ---- [C] elementwise + h store + per-wave flag ----
#pragma unroll
        for (int mi = 0; mi < 4; ++mi)
#pragma unroll
            for (int p = 0; p < 2; ++p) {
#pragma unroll
                for (int r = 0; r < 4; ++r) {
                    gs_lds[wv][quad * 4 + r][col]      = acc[mi][2 * p][r];
                    gs_lds[wv][quad * 4 + r][col + 16] = acc[mi][2 * p + 1][r];
                }
                int v = lane * 2;
                int u = v & 7, m = (v >> 3) & 15;
                float iv0 = gs_lds[wv][m][u],      fv0 = gs_lds[wv][m][8 + u];
                float gv0 = gs_lds[wv][m][16 + u], ov0 = gs_lds[wv][m][24 + u];
                float iv1 = gs_lds[wv][m][u + 1],      fv1 = gs_lds[wv][m][9 + u];
                float gv1 = gs_lds[wv][m][17 + u], ov1 = gs_lds[wv][m][25 + u];
                int uw = p * 8 + u;                       // unit-local in wave (0..15)
                int bl = mi * 16 + m;                     // batch-local (0..63)
                float c0 = c_lds[wv][uw][bl], c1 = c_lds[wv][uw + 1][bl];
                float cn0 = sigf(fv0) * c0 + sigf(iv0) * tanh_(gv0);
                float cn1 = sigf(fv1) * c1 + sigf(iv1) * tanh_(gv1);
                float hn0 = sigf(ov0) * tanh_(cn0);
                float hn1 = sigf(ov1) * tanh_(cn1);
                c_lds[wv][uw][bl] = cn0; c_lds[wv][uw + 1][bl] = cn1;
                union { bf16 e[2]; unsigned uu; } pk;
                pk.e[0] = __float2bfloat16(hn0); pk.e[1] = __float2bfloat16(hn1);
                st_coh_u32(&hbuf[HIDX(pw, l, batch0 + bl, s * 64 + wv * 16 + uw)], pk.uu);
            }
        __builtin_amdgcn_s_waitcnt(0);                    // this wave's h stores at LLC
        if (lane == 0) st_flag(&flags[FLG(l, g, s, wv)], (unsigned)(t + 2));
    }
}

// ---------------- launch ----------------
extern "C" void kernel_launch(void* const* d_in, const int* in_sizes, int n_in,
                              void* d_out, int out_size, void* d_ws, size_t ws_size,
                              hipStream_t stream) {
    const float* states = (const float*)d_in[0];
    const float* acts   = (const float*)d_in[1];
    const float* dts    = (const float*)d_in[2];
    const float* W1     = (const float*)d_in[3];
    const float* b1     = (const float*)d_in[4];
    const float* W2     = (const float*)d_in[5];
    const float* b2     = (const float*)d_in[6];
    const float* Wih0   = (const float*)d_in[7];
    const float* Whh0   = (const float*)d_in[8];
    const float* bih0   = (const float*)d_in[9];
    const float* bhh0   = (const float*)d_in[10];
    const float* Wih    = (const float*)d_in[11];
    const float* Whh    = (const float*)d_in[12];
    const float* bih    = (const float*)d_in[13];
    const float* bhh    = (const float*)d_in[14];
    const float* Wfc    = (const float*)d_in[15];
    const float* bfc    = (const float*)d_in[16];
    float* out = (float*)d_out;

    char* w = (char*)d_ws;  // needs ~36.7 MB
    bf16*  Wp    = (bf16*)(w);                       // 8*1024*512*2   = 8,388,608
    float* biasp = (float*)(w + 8388608);            // 8*1024*4       = 32,768
    bf16*  WfcP  = (bf16*)(w + 8421376);             // 16*256*2       = 8,192
    bf16*  enc   = (bf16*)(w + 8429568);             // 512*160*2      = 163,840
    bf16*  mlp   = (bf16*)(w + 8593408);             // 512*15040*2    = 15,400,960
    float* hc    = (float*)(w + 23994368);           // 512*4096*4     = 8,388,608
    bf16*  hbuf  = (bf16*)(w + 32382976);            // 2*8*512*256*2  = 4,194,304
    unsigned* flags = (unsigned*)(w + 36577280);     // 8*8*4*4*16*4   = 65,536

    k_zero_bar<<<64, 256, 0, stream>>>(flags);
    k_pack<<<8192, 128, 0, stream>>>(Wih0, Whh0, bih0, bhh0, Wih, Whh, bih, bhh, Wp, biasp);
    k_pack_fc<<<1, 256, 0, stream>>>(Wfc, WfcP);
    k_build_enc<<<(B_SZ * 160 + 255) / 256, 256, 0, stream>>>(states, acts, enc);
    k_gemm1<<<8 * 235, 256, 0, stream>>>(enc, W1, b1, mlp);
    k_gemm2<<<256, 256, 0, stream>>>(mlp, W2, b2, hc);
    k_rollout<<<256, 256, 0, stream>>>(states, acts, dts, bfc, Wp, biasp, WfcP, hc, hbuf, flags, out);
}